// Round 2
// baseline (1040.241 us; speedup 1.0000x reference)
//
#include <hip/hip_runtime.h>
#include <hip/hip_bf16.h>
#include <math.h>

typedef __bf16 bf16;
typedef __bf16 bf16x4 __attribute__((ext_vector_type(4)));
typedef __bf16 bf16x8 __attribute__((ext_vector_type(8)));
typedef float f32x4 __attribute__((ext_vector_type(4)));

#define NSENT 8000
#define LL 120
#define OCC 230
#define NRELS 53
#define XLEN 7824  // 122*60 + pad; max A-read idx = 127*60+191 = 7811

union FragU { bf16x8 v8; bf16x4 v4[2]; bf16 e[8]; };

__global__ __launch_bounds__(256, 1)
void pcnn_main(const int* __restrict__ words, const int* __restrict__ posi,
               const float* __restrict__ w2v, const float* __restrict__ p1e,
               const float* __restrict__ p2e, const float* __restrict__ convw,
               const float* __restrict__ cb0, const float* __restrict__ cb1,
               const float* __restrict__ cb2, const float* __restrict__ remb,
               const float* __restrict__ rbias, float* __restrict__ logp_ws)
{
  __shared__ __align__(16) bf16 xflat[XLEN];
  __shared__ int piece[128];
  __shared__ int words_lds[120];
  __shared__ int pos_lds[240];
  __shared__ float fl[704];
  __shared__ float partial[4][64];

  const int t = threadIdx.x;
  const int n = blockIdx.x;
  const int wv = t >> 6;
  const int lane = t & 63;
  const int g = lane >> 4;   // k-subgroup
  const int cl = lane & 15;  // row (A) / col (B,C)

  // ---- stage ids, zero padding regions ----
  if (t < 120) words_lds[t] = words[n * LL + t];
  if (t < 240) pos_lds[t] = posi[n * 240 + t];
  if (t < 624) { const int idx = (t < 60) ? t : (7200 + t); xflat[idx] = (bf16)0.0f; }
  if (t < 14) fl[690 + t] = 0.0f;

  // ---- conv-weight fragments in registers (one-time per block), f32 -> bf16 ----
  // wave wv owns oc tiles nt = wv*4 .. wv*4+3 (oc padded to 256, zeros >=230; k padded to 192, zeros >=180)
  FragU Bf[4][6];
#pragma unroll
  for (int nt = 0; nt < 4; ++nt) {
    const int oc = (wv * 4 + nt) * 16 + cl;
#pragma unroll
    for (int ks = 0; ks < 6; ++ks) {
      const int k0 = ks * 32 + g * 8;
      FragU f;
      if (oc < OCC && k0 + 8 <= 180) {
        const float4 fa = *reinterpret_cast<const float4*>(convw + oc * 180 + k0);
        const float4 fb = *reinterpret_cast<const float4*>(convw + oc * 180 + k0 + 4);
        f.e[0] = (bf16)fa.x; f.e[1] = (bf16)fa.y; f.e[2] = (bf16)fa.z; f.e[3] = (bf16)fa.w;
        f.e[4] = (bf16)fb.x; f.e[5] = (bf16)fb.y; f.e[6] = (bf16)fb.z; f.e[7] = (bf16)fb.w;
      } else {
#pragma unroll
        for (int j = 0; j < 8; ++j) {
          const int k = k0 + j;
          f.e[j] = (oc < OCC && k < 180) ? (bf16)convw[oc * 180 + k] : (bf16)0.0f;
        }
      }
      Bf[nt][ks] = f;
    }
  }

  __syncthreads();

  // ---- piece ids ----
  if (t < 128) {
    int pc = 3;
    if (t < 120) {
      const bool b0 = pos_lds[2 * t] >= 30;
      const bool b1 = pos_lds[2 * t + 1] >= 30;
      pc = (b0 && b1) ? 0 : ((!b0 && !b1) ? 2 : 1);
    }
    piece[t] = pc;
  }
  // ---- embedding gather: xflat[60 + l*60 + d] = x[l][d], f32 -> bf16 ----
  for (int e = t; e < 7200; e += 256) {
    const int l = e / 60;
    const int d = e - l * 60;
    float v;
    if (d < 50)      v = w2v[words_lds[l] * 50 + d];
    else if (d < 55) v = p1e[pos_lds[2 * l] * 5 + (d - 50)];
    else             v = p2e[pos_lds[2 * l + 1] * 5 + (d - 55)];
    xflat[60 + e] = (bf16)v;
  }
  __syncthreads();

  // ---- conv GEMM: A[m][k] = xflat[m*60+k] (overlapping rows), K-loop 6x32 ----
  f32x4 acc[8][4];
  const f32x4 z4 = {0.f, 0.f, 0.f, 0.f};
#pragma unroll
  for (int mt = 0; mt < 8; ++mt)
#pragma unroll
    for (int nt = 0; nt < 4; ++nt) acc[mt][nt] = z4;

#pragma unroll
  for (int ks = 0; ks < 6; ++ks) {
    FragU a[8];
#pragma unroll
    for (int mt = 0; mt < 8; ++mt) {
      const int idx = (mt * 16 + cl) * 60 + ks * 32 + g * 8;
      a[mt].v4[0] = *reinterpret_cast<const bf16x4*>(&xflat[idx]);
      a[mt].v4[1] = *reinterpret_cast<const bf16x4*>(&xflat[idx + 4]);
    }
#pragma unroll
    for (int mt = 0; mt < 8; ++mt)
#pragma unroll
      for (int nt = 0; nt < 4; ++nt)
        acc[mt][nt] = __builtin_amdgcn_mfma_f32_16x16x32_bf16(
            a[mt].v8, Bf[nt][ks].v8, acc[mt][nt], 0, 0, 0);
  }

  // ---- piecewise masked max-pool over l (exact feat*mask max semantics) ----
  float pool[4][3];
#pragma unroll
  for (int nt = 0; nt < 4; ++nt) { pool[nt][0] = pool[nt][1] = pool[nt][2] = -INFINITY; }
#pragma unroll
  for (int mt = 0; mt < 8; ++mt) {
    const int l0 = mt * 16 + g * 4;
    const int4 pv = *reinterpret_cast<const int4*>(&piece[l0]);
    const int pcs[4] = {pv.x, pv.y, pv.z, pv.w};
#pragma unroll
    for (int r = 0; r < 4; ++r) {
      if (l0 + r < 120) {
        const int p = pcs[r];
#pragma unroll
        for (int nt = 0; nt < 4; ++nt) {
          const float v = acc[mt][nt][r];
          pool[nt][0] = fmaxf(pool[nt][0], p == 0 ? v : 0.0f);
          pool[nt][1] = fmaxf(pool[nt][1], p == 1 ? v : 0.0f);
          pool[nt][2] = fmaxf(pool[nt][2], p == 2 ? v : 0.0f);
        }
      }
    }
  }
#pragma unroll
  for (int nt = 0; nt < 4; ++nt)
#pragma unroll
    for (int p = 0; p < 3; ++p) {
      float x = pool[nt][p];
      x = fmaxf(x, __shfl_xor(x, 16));
      x = fmaxf(x, __shfl_xor(x, 32));
      pool[nt][p] = x;
    }
  if (g == 0) {
#pragma unroll
    for (int nt = 0; nt < 4; ++nt) {
      const int oc = (wv * 4 + nt) * 16 + cl;
      if (oc < OCC) {
        fl[oc]           = tanhf(pool[nt][0] + cb0[oc]);
        fl[OCC + oc]     = tanhf(pool[nt][1] + cb1[oc]);
        fl[2 * OCC + oc] = tanhf(pool[nt][2] + cb2[oc]);
      }
    }
  }
  __syncthreads();

  // ---- logits: per-wave partial dots over k-chunks (fl broadcast reads) ----
  {
    const int kbeg = wv * 176;
    const int kend = (kbeg + 176 < 690) ? (kbeg + 176) : 690;
    if (lane < NRELS) {
      const float* wrow = remb + lane * 690;
      float a2 = 0.0f;
      int k = kbeg;
      for (; k + 4 <= kend; k += 4) {
        const float4 fv = *reinterpret_cast<const float4*>(&fl[k]);
        a2 += fv.x * wrow[k] + fv.y * wrow[k + 1] +
              fv.z * wrow[k + 2] + fv.w * wrow[k + 3];
      }
      for (; k < kend; ++k) a2 += fl[k] * wrow[k];
      partial[wv][lane] = a2;
    }
  }
  __syncthreads();

  // ---- logits finalize + log_softmax (wave 0) ----
  if (wv == 0) {
    float x = -INFINITY;
    if (lane < NRELS)
      x = (partial[0][lane] + partial[1][lane] + partial[2][lane] + partial[3][lane]) * 0.5f
          + rbias[lane];
    float m = x;
#pragma unroll
    for (int off = 32; off; off >>= 1) m = fmaxf(m, __shfl_xor(m, off));
    const float e = (lane < NRELS) ? __expf(x - m) : 0.0f;
    float s = e;
#pragma unroll
    for (int off = 32; off; off >>= 1) s += __shfl_xor(s, off);
    if (lane < NRELS) logp_ws[n * NRELS + lane] = x - m - __logf(s);
  }
}

__global__ void pcnn_bagmax(const float* __restrict__ logp, float* __restrict__ out) {
  const int idx = blockIdx.x * 256 + threadIdx.x;
  if (idx >= 1000 * NRELS) return;
  const int gg = idx / NRELS;
  const int r = idx - gg * NRELS;
  const float* p = logp + gg * 8 * NRELS + r;
  float m = p[0];
#pragma unroll
  for (int s = 1; s < 8; ++s) m = fmaxf(m, p[s * NRELS]);
  out[idx] = m;
}

extern "C" void kernel_launch(void* const* d_in, const int* in_sizes, int n_in,
                              void* d_out, int out_size, void* d_ws, size_t ws_size,
                              hipStream_t stream) {
  const int* words  = (const int*)d_in[0];
  const int* posi   = (const int*)d_in[1];
  const float* w2v  = (const float*)d_in[2];
  const float* p1e  = (const float*)d_in[3];
  const float* p2e  = (const float*)d_in[4];
  const float* cw   = (const float*)d_in[5];
  const float* cb0  = (const float*)d_in[6];
  const float* cb1  = (const float*)d_in[7];
  const float* cb2  = (const float*)d_in[8];
  const float* remb = (const float*)d_in[9];
  const float* rbias= (const float*)d_in[10];
  float* ws = (float*)d_ws;
  float* out = (float*)d_out;

  pcnn_main<<<NSENT, 256, 0, stream>>>(words, posi, w2v, p1e, p2e, cw,
                                       cb0, cb1, cb2, remb, rbias, ws);
  pcnn_bagmax<<<(1000 * NRELS + 255) / 256, 256, 0, stream>>>(ws, out);
}

// Round 3
// 556.283 us; speedup vs baseline: 1.8700x; 1.8700x over previous
//
#include <hip/hip_runtime.h>
#include <hip/hip_bf16.h>
#include <math.h>

typedef __bf16 bf16;
typedef __bf16 bf16x4 __attribute__((ext_vector_type(4)));
typedef __bf16 bf16x8 __attribute__((ext_vector_type(8)));
typedef float f32x4 __attribute__((ext_vector_type(4)));

#define OCC 230
#define NRELS 53
#define W2VE 2500000          // w2v bf16 elems in ws
#define PCATE 37210           // 61*61*10

union FragU { bf16x8 v8; bf16x4 v4[2]; bf16 e[8]; };

// ---- prep: f32 -> bf16 w2v copy + pos-concat table pcat[v1*61+v2][10] ----
__global__ void pcnn_prep(const float* __restrict__ w2v, const float* __restrict__ p1e,
                          const float* __restrict__ p2e, bf16* __restrict__ wsb) {
  const int i = blockIdx.x * 256 + threadIdx.x;
  if (i < 625000) {
    const float4 f = *reinterpret_cast<const float4*>(w2v + 4 * i);
    bf16x4 v = {(bf16)f.x, (bf16)f.y, (bf16)f.z, (bf16)f.w};
    *reinterpret_cast<bf16x4*>(wsb + 4 * i) = v;
  } else {
    const int e = i - 625000;
    if (e < PCATE) {
      const int row = e / 10, c = e - row * 10;
      const int v1 = row / 61, v2 = row - v1 * 61;
      const float f = (c < 5) ? p1e[v1 * 5 + c] : p2e[v2 * 5 + (c - 5)];
      wsb[W2VE + e] = (bf16)f;
    }
  }
}

__global__ __launch_bounds__(512, 2)
void pcnn_bag(const int* __restrict__ words, const int* __restrict__ posi,
              const float* __restrict__ convw,
              const float* __restrict__ cb0, const float* __restrict__ cb1,
              const float* __restrict__ cb2, const float* __restrict__ remb,
              const float* __restrict__ rbias, const bf16* __restrict__ wsb,
              float* __restrict__ out)
{
  __shared__ __align__(16) bf16 xflat[2][8256];  // [buf][elem]; A[m][k]=xflat[m*60+k+? base 60]
  __shared__ int widx[960];    // word | (pidx<<16), per (s,l)
  __shared__ int piece[960];
  __shared__ float fl[704];
  __shared__ float partial[8][56];
  __shared__ float logp[8][56];

  const int t = threadIdx.x;
  const int b = blockIdx.x;
  const int wv = t >> 6;     // 0..7
  const int lane = t & 63;
  const int g = lane >> 4;
  const int cl = lane & 15;

  // ---- bag ids: words/pos for all 8 sentences; pack word+pidx; piece ids ----
  for (int i = t; i < 960; i += 512) {
    const int w = words[b * 960 + i];
    const int2 pp = *reinterpret_cast<const int2*>(posi + b * 1920 + 2 * i);
    widx[i] = w | ((pp.x * 61 + pp.y) << 16);
    const bool b0 = pp.x >= 30, b1 = pp.y >= 30;
    piece[i] = (b0 && b1) ? 0 : ((!b0 && !b1) ? 2 : 1);
  }
  if (t < 60) { xflat[0][t] = (bf16)0.0f; xflat[1][t] = (bf16)0.0f; }  // leading pad rows

  // ---- conv weights -> registers (once per bag). wave wv owns oc tiles 2wv, 2wv+1 ----
  FragU Bf[2][6];
#pragma unroll
  for (int nt = 0; nt < 2; ++nt) {
    const int oc = (wv * 2 + nt) * 16 + cl;
#pragma unroll
    for (int ks = 0; ks < 6; ++ks) {
      const int k0 = ks * 32 + g * 8;
      FragU f;
      if (oc < OCC && k0 + 8 <= 180) {
        const float4 fa = *reinterpret_cast<const float4*>(convw + oc * 180 + k0);
        const float4 fb = *reinterpret_cast<const float4*>(convw + oc * 180 + k0 + 4);
        f.e[0] = (bf16)fa.x; f.e[1] = (bf16)fa.y; f.e[2] = (bf16)fa.z; f.e[3] = (bf16)fa.w;
        f.e[4] = (bf16)fb.x; f.e[5] = (bf16)fb.y; f.e[6] = (bf16)fb.z; f.e[7] = (bf16)fb.w;
      } else {
#pragma unroll
        for (int j = 0; j < 8; ++j) {
          const int k = k0 + j;
          f.e[j] = (oc < OCC && k < 180) ? (bf16)convw[oc * 180 + k] : (bf16)0.0f;
        }
      }
      Bf[nt][ks] = f;
    }
  }
  const float rb = (wv == 0 && lane < NRELS) ? rbias[lane] : 0.0f;
  __syncthreads();  // widx ready

  // ---- async gather issue: sentence s embeddings -> xflat[nb] (bf16 dword pairs) ----
  auto issue_gather = [&](int s, int nb) {
#pragma unroll
    for (int j = 0; j < 8; ++j) {
      int q = j * 512 + wv * 64 + lane;     // bf16-pair index; dest elem = 60+2q
      q = (q < 3600) ? q : 3599;            // clamp source (tail lanes duplicate)
      const int l = q / 30;
      const int c = q - l * 30;
      const int wi = widx[s * 120 + l];
      const int word = wi & 0xFFFF;
      const int pidx = wi >> 16;
      const int off = (c < 25) ? (word * 50 + 2 * c)
                               : (W2VE + pidx * 10 + 2 * c - 50);
      const bf16* src = wsb + off;
      bf16* dst = &xflat[nb][60 + j * 1024 + wv * 128];  // wave-uniform; HW adds lane*4B
      __builtin_amdgcn_global_load_lds(
          (const __attribute__((address_space(1))) void*)src,
          (__attribute__((address_space(3))) void*)dst, 4, 0, 0);
    }
  };

  issue_gather(0, 0);
  asm volatile("s_waitcnt vmcnt(0)" ::: "memory");
  __syncthreads();  // xflat[0] gather landed (all waves)

  for (int s = 0; s < 8; ++s) {
    const int nb = s & 1;
    if (s < 7) issue_gather(s + 1, nb ^ 1);          // async, lands during compute
    if (t < 60) xflat[nb][7260 + t] = (bf16)0.0f;     // re-zero row-119 window tail
    __syncthreads();

    // ---- conv GEMM: 96 MFMA/wave (8 m-tiles x 2 n-tiles x 6 k-steps) ----
    f32x4 acc[8][2];
    const f32x4 z4 = {0.f, 0.f, 0.f, 0.f};
#pragma unroll
    for (int mt = 0; mt < 8; ++mt) { acc[mt][0] = z4; acc[mt][1] = z4; }
#pragma unroll
    for (int ks = 0; ks < 6; ++ks) {
      FragU a[8];
#pragma unroll
      for (int mt = 0; mt < 8; ++mt) {
        const int idx = (mt * 16 + cl) * 60 + ks * 32 + g * 8;
        a[mt].v4[0] = *reinterpret_cast<const bf16x4*>(&xflat[nb][idx]);
        a[mt].v4[1] = *reinterpret_cast<const bf16x4*>(&xflat[nb][idx + 4]);
      }
#pragma unroll
      for (int mt = 0; mt < 8; ++mt)
#pragma unroll
        for (int nt = 0; nt < 2; ++nt)
          acc[mt][nt] = __builtin_amdgcn_mfma_f32_16x16x32_bf16(
              a[mt].v8, Bf[nt][ks].v8, acc[mt][nt], 0, 0, 0);
    }

    // ---- piecewise masked max-pool (ref semantics: masked-out contributes 0) ----
    float pool[2][3];
#pragma unroll
    for (int nt = 0; nt < 2; ++nt) { pool[nt][0] = pool[nt][1] = pool[nt][2] = -INFINITY; }
#pragma unroll
    for (int mt = 0; mt < 8; ++mt) {
      const int l0 = mt * 16 + g * 4;
      if (l0 < 120) {
        const int4 pv = *reinterpret_cast<const int4*>(&piece[s * 120 + l0]);
        const int pcs[4] = {pv.x, pv.y, pv.z, pv.w};
#pragma unroll
        for (int r = 0; r < 4; ++r) {
          const int p = pcs[r];
#pragma unroll
          for (int nt = 0; nt < 2; ++nt) {
            const float v = acc[mt][nt][r];
            pool[nt][0] = fmaxf(pool[nt][0], p == 0 ? v : 0.0f);
            pool[nt][1] = fmaxf(pool[nt][1], p == 1 ? v : 0.0f);
            pool[nt][2] = fmaxf(pool[nt][2], p == 2 ? v : 0.0f);
          }
        }
      }
    }
#pragma unroll
    for (int nt = 0; nt < 2; ++nt)
#pragma unroll
      for (int p = 0; p < 3; ++p) {
        float x = pool[nt][p];
        x = fmaxf(x, __shfl_xor(x, 16));
        x = fmaxf(x, __shfl_xor(x, 32));
        pool[nt][p] = x;
      }
    if (g == 0) {
#pragma unroll
      for (int nt = 0; nt < 2; ++nt) {
        const int oc = (wv * 2 + nt) * 16 + cl;
        if (oc < OCC) {
          fl[oc]           = tanhf(pool[nt][0] + cb0[oc]);
          fl[OCC + oc]     = tanhf(pool[nt][1] + cb1[oc]);
          fl[2 * OCC + oc] = tanhf(pool[nt][2] + cb2[oc]);
        }
      }
    }
    __syncthreads();  // fl visible

    // ---- logits partials: wave wv covers k in [wv*88, min(+88,690)) ----
    {
      const int kbeg = wv * 88;
      const int kend = (kbeg + 88 < 690) ? (kbeg + 88) : 690;
      if (lane < NRELS) {
        const float* wrow = remb + lane * 690;
        float a2 = 0.0f;
        int k = kbeg;
        for (; k + 4 <= kend; k += 4) {
          const float4 fv = *reinterpret_cast<const float4*>(&fl[k]);
          a2 += fv.x * wrow[k] + fv.y * wrow[k + 1] +
                fv.z * wrow[k + 2] + fv.w * wrow[k + 3];
        }
        for (; k < kend; ++k) a2 += fl[k] * wrow[k];
        partial[wv][lane] = a2;
      }
    }
    __syncthreads();  // partials visible

    if (wv == 0) {
      float x = -INFINITY;
      if (lane < NRELS) {
        float sum = 0.0f;
#pragma unroll
        for (int j = 0; j < 8; ++j) sum += partial[j][lane];
        x = sum * 0.5f + rb;
      }
      float m = x;
#pragma unroll
      for (int off = 32; off; off >>= 1) m = fmaxf(m, __shfl_xor(m, off));
      const float e = (lane < NRELS) ? __expf(x - m) : 0.0f;
      float sm = e;
#pragma unroll
      for (int off = 32; off; off >>= 1) sm += __shfl_xor(sm, off);
      if (lane < NRELS) logp[s][lane] = x - m - __logf(sm);
    }
    asm volatile("s_waitcnt vmcnt(0)" ::: "memory");  // gather(s+1) landed (per wave)
    __syncthreads();                                   // buffer handoff + logp visible
  }

  // ---- fused bag-max ----
  if (t < NRELS) {
    float m = logp[0][t];
#pragma unroll
    for (int s2 = 1; s2 < 8; ++s2) m = fmaxf(m, logp[s2][t]);
    out[b * NRELS + t] = m;
  }
}

extern "C" void kernel_launch(void* const* d_in, const int* in_sizes, int n_in,
                              void* d_out, int out_size, void* d_ws, size_t ws_size,
                              hipStream_t stream) {
  const int* words  = (const int*)d_in[0];
  const int* posi   = (const int*)d_in[1];
  const float* w2v  = (const float*)d_in[2];
  const float* p1e  = (const float*)d_in[3];
  const float* p2e  = (const float*)d_in[4];
  const float* cw   = (const float*)d_in[5];
  const float* cb0  = (const float*)d_in[6];
  const float* cb1  = (const float*)d_in[7];
  const float* cb2  = (const float*)d_in[8];
  const float* remb = (const float*)d_in[9];
  const float* rbias= (const float*)d_in[10];
  bf16* wsb = (bf16*)d_ws;
  float* out = (float*)d_out;

  pcnn_prep<<<(625000 + PCATE + 255) / 256, 256, 0, stream>>>(w2v, p1e, p2e, wsb);
  pcnn_bag<<<1000, 512, 0, stream>>>(words, posi, cw, cb0, cb1, cb2,
                                     remb, rbias, wsb, out);
}